// Round 6
// baseline (879.838 us; speedup 1.0000x reference)
//
#include <hip/hip_runtime.h>
#include <hip/hip_bf16.h>
#include <cstdint>

// ---------------------------------------------------------------------------
// GCN 3-layer forward, bf16 feature pipeline + MFMA GEMM.
// R6: fix POOL-path double-shift bug (bflo(f2bf(r)<<16) == 0 -> pooled was
//     zeroed). Pool now accumulates fp32 relu outputs directly (closer to np
//     ref than bf16-rounded). Structure otherwise identical to R5:
//     column-slab gather (8 slabs x 16 cols, slab = blockIdx%8 -> XCD-pinned,
//     3.2MB slab fits per-XCD L2); last gather fuses mean-pool; GEMM0 reads
//     fp32 x directly.
// ---------------------------------------------------------------------------

typedef unsigned short u16;
typedef unsigned int u32;
typedef __attribute__((ext_vector_type(8))) short short8v;
typedef __attribute__((ext_vector_type(4))) float f32x4;

#define NBMAX 256
#define BKSH  9
#define SCH   2048

__device__ inline u16 f2bf(float f) {
  u32 u = __float_as_uint(f);
  u += 0x7fff + ((u >> 16) & 1);  // RNE
  return (u16)(u >> 16);
}
__device__ inline float bflo(u32 u) { return __uint_as_float(u << 16); }
__device__ inline float bfhi(u32 u) { return __uint_as_float(u & 0xffff0000u); }

// --- edge-index dtype detect ------------------------------------------------
__global__ void k_detect(const int* __restrict__ ei, int* __restrict__ mode, int e) {
  __shared__ int any;
  if (threadIdx.x == 0) any = 0;
  __syncthreads();
  int lim = min(e, 2048);
  int local = 0;
  for (int i = threadIdx.x; i < lim; i += blockDim.x)
    local |= (ei[2 * i + 1] != 0);
  if (local) atomicOr(&any, 1);
  __syncthreads();
  if (threadIdx.x == 0) mode[0] = (any == 0) ? 1 : 0;
}

__global__ void k_zero(int* __restrict__ bucketCnt, float* __restrict__ pooled, int nb) {
  int i = threadIdx.x;
  if (i < nb) bucketCnt[i] = 0;
  if (i < 128) pooled[i] = 0.0f;
}

// --- CSR build: 2-level radix by destination --------------------------------
__global__ __launch_bounds__(256) void b_count(const int* __restrict__ ei,
                                               const int* __restrict__ mode,
                                               int* __restrict__ bucketCnt,
                                               int e, int nb) {
  __shared__ int lh[NBMAX];
  int t = threadIdx.x;
  lh[t] = 0;
  __syncthreads();
  int m = mode[0];
  int stride = gridDim.x * 256;
  for (int i = blockIdx.x * 256 + t; i < e; i += stride) {
    long long di = (long long)e + i;
    int d = m ? ei[2 * di] : ei[di];
    atomicAdd(&lh[d >> BKSH], 1);
  }
  __syncthreads();
  if (t < nb && lh[t]) atomicAdd(&bucketCnt[t], lh[t]);
}

__global__ __launch_bounds__(256) void b_bscan(const int* __restrict__ bucketCnt,
                                               int* __restrict__ bucketOff,
                                               int* __restrict__ bucketCur,
                                               int nb, int e) {
  __shared__ int sh[NBMAX];
  int t = threadIdx.x;
  int c = (t < nb) ? bucketCnt[t] : 0;
  sh[t] = c;
  __syncthreads();
  for (int d = 1; d < NBMAX; d <<= 1) {
    int v = (t >= d) ? sh[t - d] : 0;
    __syncthreads();
    sh[t] += v;
    __syncthreads();
  }
  int ex = sh[t] - c;
  if (t < nb) { bucketOff[t] = ex; bucketCur[t] = ex; }
  if (t == 0) bucketOff[nb] = e;
}

__global__ __launch_bounds__(256) void b_scatter(const int* __restrict__ ei,
                                                 const int* __restrict__ mode,
                                                 int* __restrict__ bucketCur,
                                                 int* __restrict__ pairBuf,
                                                 int e, int nb) {
  __shared__ int cnt[NBMAX];
  __shared__ int pre[NBMAX];
  __shared__ int base[NBMAX];
  __shared__ int stage[2 * SCH];
  const int t = threadIdx.x;
  const int chunk0 = blockIdx.x * SCH;
  const int nloc = min(SCH, e - chunk0);
  const int m = mode[0];

  cnt[t] = 0;
  __syncthreads();

  int myS[SCH / 256], myD[SCH / 256], myB[SCH / 256], mySlot[SCH / 256];
#pragma unroll
  for (int j = 0; j < SCH / 256; ++j) {
    int li = j * 256 + t;
    myB[j] = -1;
    if (li < nloc) {
      int i = chunk0 + li;
      long long di = (long long)e + i;
      int s = m ? ei[2 * (long long)i] : ei[i];
      int d = m ? ei[2 * di] : ei[di];
      int b = d >> BKSH;
      myS[j] = s; myD[j] = d; myB[j] = b;
      mySlot[j] = atomicAdd(&cnt[b], 1);
    }
  }
  __syncthreads();

  int c0 = cnt[t];
  pre[t] = c0;
  __syncthreads();
  for (int d = 1; d < NBMAX; d <<= 1) {
    int v = (t >= d) ? pre[t - d] : 0;
    __syncthreads();
    pre[t] += v;
    __syncthreads();
  }
  int myPre = pre[t] - c0;
  if (t < nb && c0 > 0) base[t] = atomicAdd(&bucketCur[t], c0);
  __syncthreads();
  cnt[t] = myPre;
  __syncthreads();

#pragma unroll
  for (int j = 0; j < SCH / 256; ++j) {
    if (myB[j] >= 0) {
      int si = cnt[myB[j]] + mySlot[j];
      stage[2 * si] = myS[j];
      stage[2 * si + 1] = myD[j];
    }
  }
  __syncthreads();

  int wave = t >> 6, lane = t & 63;
  for (int b = wave; b < nb; b += 4) {
    int cb = pre[b] - cnt[b];
    if (cb <= 0) continue;
    int lo = cnt[b];
    size_t gb = (size_t)base[b];
    for (int j = lane; j < 2 * cb; j += 64)
      pairBuf[2 * gb + j] = stage[2 * lo + j];
  }
}

__global__ __launch_bounds__(512) void b_fine(const int* __restrict__ pairBuf,
                                              const int* __restrict__ bucketOff,
                                              int* __restrict__ offs,
                                              float* __restrict__ dis,
                                              int* __restrict__ csr,
                                              int n, int e) {
  const int b = blockIdx.x;
  const int d0 = b << BKSH;
  const int lo = bucketOff[b], hi = bucketOff[b + 1];
  __shared__ int arr[1 << BKSH];
  __shared__ int cur[1 << BKSH];
  const int t = threadIdx.x;
  arr[t] = 0; cur[t] = 0;
  __syncthreads();
  for (int i = lo + t; i < hi; i += 512) {
    int d = pairBuf[2 * (size_t)i + 1];
    atomicAdd(&arr[d - d0], 1);
  }
  __syncthreads();
  int c0 = arr[t];
  __syncthreads();
  for (int dd = 1; dd < 512; dd <<= 1) {
    int v = (t >= dd) ? arr[t - dd] : 0;
    __syncthreads();
    arr[t] += v;
    __syncthreads();
  }
  int epre = arr[t] - c0;
  int gd = d0 + t;
  if (gd < n) {
    offs[gd] = lo + epre;
    dis[gd] = rsqrtf((float)c0 + 1.0f);
  }
  __syncthreads();
  arr[t] = epre;
  __syncthreads();
  for (int i = lo + t; i < hi; i += 512) {
    int s = pairBuf[2 * (size_t)i];
    int d = pairBuf[2 * (size_t)i + 1];
    int ld = d - d0;
    int p = lo + arr[ld] + atomicAdd(&cur[ld], 1);
    csr[p] = s;
  }
  if (b == 0 && t == 0) offs[n] = e;
}

// --- pack W[128][128] fp32 -> MFMA B-fragments bf16 -------------------------
__global__ __launch_bounds__(256) void k_wpack(const float* __restrict__ W,
                                               u16* __restrict__ wp) {
  int f = blockIdx.x * 256 + threadIdx.x;
  if (f >= 2048) return;
  int ct = f >> 8, kc = (f >> 6) & 3, lane = f & 63;
  int g = lane >> 4, c = lane & 15;
  u32 o[4];
#pragma unroll
  for (int q = 0; q < 4; ++q) {
    int k = kc * 32 + g * 8 + q * 2;
    u16 e0 = f2bf(W[(size_t)k * 128 + ct * 16 + c]);
    u16 e1 = f2bf(W[(size_t)(k + 1) * 128 + ct * 16 + c]);
    o[q] = (u32)e0 | ((u32)e1 << 16);
  }
  uint4 v; v.x = o[0]; v.y = o[1]; v.z = o[2]; v.w = o[3];
  *reinterpret_cast<uint4*>(wp + (size_t)f * 8) = v;
}

// --- GEMM: tmp[r,:] = bf16( dis[r] * (h[r,:] @ W) ) via MFMA ----------------
// FP32IN: read h rows as fp32 (layer 0 reads x directly), else bf16.
template <bool FP32IN>
__global__ __launch_bounds__(256) void k_gemm_mfma(const void* __restrict__ hin,
                                                   const u16* __restrict__ wp,
                                                   const float* __restrict__ dis,
                                                   u16* __restrict__ tmpb, int n) {
  __shared__ float eps[64 * 132];
  const int tid = threadIdx.x;
  const int w = tid >> 6, l = tid & 63;
  const int g = l >> 4, c16 = l & 15;
  const int rowbase = blockIdx.x * 64 + w * 16;

  const short8v zero8 = {0, 0, 0, 0, 0, 0, 0, 0};
  short8v a[4];
  int ar = rowbase + c16;
  bool aok = ar < n;
#pragma unroll
  for (int kc = 0; kc < 4; ++kc) {
    if (FP32IN) {
      const float* hrow = (const float*)hin + (size_t)ar * 128;
      short8v s = zero8;
      if (aok) {
        float4 v0 = *reinterpret_cast<const float4*>(hrow + kc * 32 + g * 8);
        float4 v1 = *reinterpret_cast<const float4*>(hrow + kc * 32 + g * 8 + 4);
        s[0] = (short)f2bf(v0.x); s[1] = (short)f2bf(v0.y);
        s[2] = (short)f2bf(v0.z); s[3] = (short)f2bf(v0.w);
        s[4] = (short)f2bf(v1.x); s[5] = (short)f2bf(v1.y);
        s[6] = (short)f2bf(v1.z); s[7] = (short)f2bf(v1.w);
      }
      a[kc] = s;
    } else {
      const u16* hrow = (const u16*)hin + (size_t)ar * 128;
      a[kc] = aok ? *reinterpret_cast<const short8v*>(hrow + kc * 32 + g * 8) : zero8;
    }
  }

  f32x4 acc[8];
#pragma unroll
  for (int ct = 0; ct < 8; ++ct) acc[ct] = f32x4{0.f, 0.f, 0.f, 0.f};

#pragma unroll
  for (int ct = 0; ct < 8; ++ct) {
#pragma unroll
    for (int kc = 0; kc < 4; ++kc) {
      short8v b = *reinterpret_cast<const short8v*>(wp + ((size_t)(ct * 4 + kc) * 64 + l) * 8);
      acc[ct] = __builtin_amdgcn_mfma_f32_16x16x32_bf16(a[kc], b, acc[ct], 0, 0, 0);
    }
  }

#pragma unroll
  for (int j = 0; j < 4; ++j) {
    int rl = w * 16 + g * 4 + j;
    int gr = blockIdx.x * 64 + rl;
    float dn = (gr < n) ? dis[gr] : 0.f;
#pragma unroll
    for (int ct = 0; ct < 8; ++ct)
      eps[rl * 132 + ct * 16 + c16] = acc[ct][j] * dn;
  }
  __syncthreads();

  int rl = tid >> 2, seg = tid & 3;
  int gr = blockIdx.x * 64 + rl;
  if (gr < n) {
    const float* src = &eps[rl * 132 + seg * 32];
#pragma unroll
    for (int q = 0; q < 4; ++q) {
      float4 v0 = *reinterpret_cast<const float4*>(src + q * 8);
      float4 v1 = *reinterpret_cast<const float4*>(src + q * 8 + 4);
      uint4 o;
      o.x = (u32)f2bf(v0.x) | ((u32)f2bf(v0.y) << 16);
      o.y = (u32)f2bf(v0.z) | ((u32)f2bf(v0.w) << 16);
      o.z = (u32)f2bf(v1.x) | ((u32)f2bf(v1.y) << 16);
      o.w = (u32)f2bf(v1.z) | ((u32)f2bf(v1.w) << 16);
      *reinterpret_cast<uint4*>(tmpb + (size_t)gr * 128 + seg * 32 + q * 8) = o;
    }
  }
}

// --- column-slab gather -----------------------------------------------------
// slab = blockIdx%8 (XCD round-robin): slab working set 3.2MB fits XCD L2.
// 256 thr = 64 streams of 4 lanes; stream handles 2 nodes; 4 lanes x uint2
// = 32B = one 16-col slab row. POOL: last layer, accumulate fp32 mean-pool
// partials instead of writing hout.
template <bool POOL>
__global__ __launch_bounds__(256) void k_gather_slab(const u16* __restrict__ tmpb,
                                                     const int* __restrict__ csr,
                                                     const int* __restrict__ offs,
                                                     const float* __restrict__ dis,
                                                     const float* __restrict__ bias,
                                                     u16* __restrict__ houtb,
                                                     float* __restrict__ pooled,
                                                     int n) {
  __shared__ float pp[16];
  const int slab = blockIdx.x & 7;
  const int nblk = blockIdx.x >> 3;
  const int tid = threadIdx.x;
  const int stream = tid >> 2;
  const int lane4 = tid & 3;
  const size_t off32 = (size_t)slab * 4 + lane4;  // uint2 index within row
  const uint2* tp = reinterpret_cast<const uint2*>(tmpb);

  if (POOL) {
    if (tid < 16) pp[tid] = 0.f;
    __syncthreads();
  }

  float4 bb = reinterpret_cast<const float4*>(bias)[slab * 4 + lane4];

#pragma unroll
  for (int u = 0; u < 2; ++u) {
    int nd = nblk * 128 + stream * 2 + u;
    float r0 = 0.f, r1 = 0.f, r2 = 0.f, r3 = 0.f;
    if (nd < n) {
      int s0 = offs[nd], s1 = offs[nd + 1];
      float a0 = 0.f, a1 = 0.f, a2 = 0.f, a3 = 0.f;
      float c0 = 0.f, c1 = 0.f, c2 = 0.f, c3 = 0.f;
      int ee = s0;
      for (; ee + 1 < s1; ee += 2) {
        uint2 ua = tp[(size_t)csr[ee] * 32 + off32];
        uint2 ub = tp[(size_t)csr[ee + 1] * 32 + off32];
        a0 += bflo(ua.x); a1 += bfhi(ua.x); a2 += bflo(ua.y); a3 += bfhi(ua.y);
        c0 += bflo(ub.x); c1 += bfhi(ub.x); c2 += bflo(ub.y); c3 += bfhi(ub.y);
      }
      if (ee < s1) {
        uint2 ua = tp[(size_t)csr[ee] * 32 + off32];
        a0 += bflo(ua.x); a1 += bfhi(ua.x); a2 += bflo(ua.y); a3 += bfhi(ua.y);
      }
      uint2 us = tp[(size_t)nd * 32 + off32];
      float sx0 = a0 + c0 + bflo(us.x);
      float sx1 = a1 + c1 + bfhi(us.x);
      float sx2 = a2 + c2 + bflo(us.y);
      float sx3 = a3 + c3 + bfhi(us.y);
      float dn = dis[nd];
      r0 = fmaf(dn, sx0, bb.x); r0 = r0 > 0.f ? r0 : 0.f;
      r1 = fmaf(dn, sx1, bb.y); r1 = r1 > 0.f ? r1 : 0.f;
      r2 = fmaf(dn, sx2, bb.z); r2 = r2 > 0.f ? r2 : 0.f;
      r3 = fmaf(dn, sx3, bb.w); r3 = r3 > 0.f ? r3 : 0.f;
      if (!POOL) {
        uint2 o;
        o.x = (u32)f2bf(r0) | ((u32)f2bf(r1) << 16);
        o.y = (u32)f2bf(r2) | ((u32)f2bf(r3) << 16);
        reinterpret_cast<uint2*>(houtb)[(size_t)nd * 32 + off32] = o;
      }
    }
    if (POOL) {
      // accumulate fp32 relu outputs directly (matches np ref's fp32 pool)
      atomicAdd(&pp[lane4 * 4 + 0], r0);
      atomicAdd(&pp[lane4 * 4 + 1], r1);
      atomicAdd(&pp[lane4 * 4 + 2], r2);
      atomicAdd(&pp[lane4 * 4 + 3], r3);
    }
  }

  if (POOL) {
    __syncthreads();
    if (tid < 16) atomicAdd(&pooled[slab * 16 + tid], pp[tid]);
  }
}

__global__ void k_final(const float* __restrict__ pooled, const float* __restrict__ Wfc,
                        const float* __restrict__ bfc, float* __restrict__ out,
                        float invn) {
  int j = threadIdx.x;
  if (j < 32) {
    float acc = 0.f;
    for (int k = 0; k < 128; ++k) acc = fmaf(pooled[k], Wfc[k * 32 + j], acc);
    out[j] = fmaf(acc, invn, bfc[j]);
  }
}

extern "C" void kernel_launch(void* const* d_in, const int* in_sizes, int n_in,
                              void* d_out, int out_size, void* d_ws, size_t ws_size,
                              hipStream_t stream) {
  const float* x   = (const float*)d_in[0];
  const int*   ei  = (const int*)d_in[1];
  const float* W0  = (const float*)d_in[2];
  const float* b0  = (const float*)d_in[3];
  const float* W1  = (const float*)d_in[4];
  const float* b1  = (const float*)d_in[5];
  const float* W2  = (const float*)d_in[6];
  const float* b2  = (const float*)d_in[7];
  const float* Wfc = (const float*)d_in[8];
  const float* bfc = (const float*)d_in[9];

  const int n = in_sizes[0] / 128;
  const int e = in_sizes[1] / 2;
  const int nb = (n + (1 << BKSH) - 1) >> BKSH;

  char* ws = (char*)d_ws;
  size_t off = 0;
  auto alloc = [&](size_t bytes) -> void* {
    void* p = ws + off;
    off = (off + bytes + 255) & ~(size_t)255;
    return p;
  };
  int*   mode      = (int*)alloc(sizeof(int));
  int*   bucketCnt = (int*)alloc(NBMAX * 4);
  int*   bucketOff = (int*)alloc((NBMAX + 1) * 4);
  int*   bucketCur = (int*)alloc(NBMAX * 4);
  int*   offs      = (int*)alloc((size_t)(n + 1) * 4);
  float* dis       = (float*)alloc((size_t)n * 4);
  int*   csr       = (int*)alloc((size_t)e * 4);
  float* pooled    = (float*)alloc(128 * 4);
  u16*   wp        = (u16*)alloc(3 * 2048 * 8 * 2);
  u16*   tmpb      = (u16*)alloc((size_t)n * 128 * 2);
  u16*   houtb     = (u16*)alloc((size_t)n * 128 * 2);
  int*   pairBuf   = (int*)tmpb;  // alias: pairs consumed (b_fine) before gemm0

  k_detect<<<1, 256, 0, stream>>>(ei, mode, e);
  k_zero<<<1, 256, 0, stream>>>(bucketCnt, pooled, nb);
  b_count<<<192, 256, 0, stream>>>(ei, mode, bucketCnt, e, nb);
  b_bscan<<<1, 256, 0, stream>>>(bucketCnt, bucketOff, bucketCur, nb, e);
  b_scatter<<<(e + SCH - 1) / SCH, 256, 0, stream>>>(ei, mode, bucketCur, pairBuf, e, nb);
  b_fine<<<nb, 512, 0, stream>>>(pairBuf, bucketOff, offs, dis, csr, n, e);

  k_wpack<<<8, 256, 0, stream>>>(W0, wp);
  k_wpack<<<8, 256, 0, stream>>>(W1, wp + 2048 * 8);
  k_wpack<<<8, 256, 0, stream>>>(W2, wp + 2 * 2048 * 8);

  int gg = (n + 63) / 64;
  int gslab = 8 * ((n + 127) / 128);

  // layer 0 (reads fp32 x directly)
  k_gemm_mfma<true><<<gg, 256, 0, stream>>>(x, wp, dis, tmpb, n);
  k_gather_slab<false><<<gslab, 256, 0, stream>>>(tmpb, csr, offs, dis, b0, houtb, pooled, n);
  // layer 1
  k_gemm_mfma<false><<<gg, 256, 0, stream>>>(houtb, wp + 2048 * 8, dis, tmpb, n);
  k_gather_slab<false><<<gslab, 256, 0, stream>>>(tmpb, csr, offs, dis, b1, houtb, pooled, n);
  // layer 2 (gather fuses mean-pool, no hout write)
  k_gemm_mfma<false><<<gg, 256, 0, stream>>>(houtb, wp + 2 * 2048 * 8, dis, tmpb, n);
  k_gather_slab<true><<<gslab, 256, 0, stream>>>(tmpb, csr, offs, dis, b2, houtb, pooled, n);

  k_final<<<1, 32, 0, stream>>>(pooled, Wfc, bfc, (float*)d_out, 1.0f / (float)n);
}